// Round 3
// baseline (15687.856 us; speedup 1.0000x reference)
//
#include <hip/hip_runtime.h>
#include <stdint.h>

#define N_NEUR 4096
#define N_IN   512
#define BATCH  8
#define TSTEPS 1000
#define KB_REC 128                 // 128 k-blocks of 32 for recurrent W
#define KB_TOT 144                 // + 16 k-blocks for feedforward (K = 4608)
#define KB_PW  18                  // k-blocks per wave (144 / 8 waves)
#define STRIDE_OUT (BATCH * TSTEPS * N_NEUR)

#define BETA_E_F 0.95122942450071400910f
#define BETA_I_F 0.90483741803595957316f
#define ALPHA_F  0.81873075307798185867f
#define RC_E_F   (100.0f * (1.0f - BETA_E_F))
#define RC_I_F   (100.0f * (1.0f - BETA_I_F))
#define U_REST_F  (-65.0f)
#define THETA_F   (-50.0f)
#define U_RESET_F (-65.0f)

typedef __attribute__((ext_vector_type(8))) short short8;
typedef __attribute__((ext_vector_type(4))) float f32x4;
typedef __attribute__((ext_vector_type(4))) int   i32x4;

// B-fragment-packed weights: [stripe 256][kb 144][lane 64][j 8] bf16
__device__ __attribute__((aligned(16))) uint16_t g_B[256 * KB_TOT * 512];
__device__ __attribute__((aligned(16))) uint8_t  g_sb[2 * N_NEUR];     // spike bytes (bit b = batch b), dbuf
__device__ __attribute__((aligned(16))) uint8_t  g_inb[TSTEPS * N_IN]; // input bitmask bytes
__device__ float    g_I[BATCH * N_NEUR];
__device__ float    g_vr[BATCH * N_NEUR];
__device__ uint32_t g_cnt[TSTEPS + 2];    // arrival counters per step (pre-zeroed each call)

__device__ __forceinline__ uint16_t f2bf(float v) {
    uint32_t x = __float_as_uint(v);
    uint32_t r = x + 0x7FFFu + ((x >> 16) & 1u);
    return (uint16_t)(r >> 16);
}

__global__ void prep_w(const float* __restrict__ W, const int* __restrict__ types) {
    int o = blockIdx.x * 256 + threadIdx.x;          // 2,097,152 threads
    int lane = o & 63, kb = (o >> 6) & 127, stripe = o >> 13;
    int col = (stripe << 4) + (lane & 15);
    float scale = (types[col] == 1) ? 0.5f : 2.0f;
    int kbase = kb * 32 + ((lane >> 4) & 3) * 8;
    uint32_t u[4];
#pragma unroll
    for (int p = 0; p < 4; ++p) {
        float v0 = W[(size_t)(kbase + 2 * p) * N_NEUR + col] * scale;
        float v1 = W[(size_t)(kbase + 2 * p + 1) * N_NEUR + col] * scale;
        u[p] = (uint32_t)f2bf(v0) | ((uint32_t)f2bf(v1) << 16);
    }
    i32x4 iv = { (int)u[0], (int)u[1], (int)u[2], (int)u[3] };
    ((short8*)g_B)[(stripe * KB_TOT + kb) * 64 + lane] = __builtin_bit_cast(short8, iv);
}

__global__ void prep_ff(const float* __restrict__ FF) {
    int o = blockIdx.x * 256 + threadIdx.x;          // 262,144 threads
    int lane = o & 63, kbl = (o >> 6) & 15, stripe = o >> 10;
    int col = (stripe << 4) + (lane & 15);
    int kbase = kbl * 32 + ((lane >> 4) & 3) * 8;
    uint32_t u[4];
#pragma unroll
    for (int p = 0; p < 4; ++p) {
        float v0 = FF[(size_t)(kbase + 2 * p) * N_NEUR + col];
        float v1 = FF[(size_t)(kbase + 2 * p + 1) * N_NEUR + col];
        u[p] = (uint32_t)f2bf(v0) | ((uint32_t)f2bf(v1) << 16);
    }
    i32x4 iv = { (int)u[0], (int)u[1], (int)u[2], (int)u[3] };
    ((short8*)g_B)[(stripe * KB_TOT + 128 + kbl) * 64 + lane] = __builtin_bit_cast(short8, iv);
}

__global__ void prep_in(const float* __restrict__ inp) {
    const int total = TSTEPS * N_IN;
    for (int o = blockIdx.x * 256 + threadIdx.x; o < total; o += gridDim.x * 256) {
        int t = o >> 9, i = o & 511;
        uint32_t m = 0;
#pragma unroll
        for (int b = 0; b < 8; ++b) {
            float v = inp[(size_t)(b * TSTEPS + t) * N_IN + i];
            m |= (v != 0.0f ? 1u : 0u) << b;
        }
        g_inb[o] = (uint8_t)m;
    }
}

__global__ void k_zero() {
    int i = blockIdx.x * 256 + threadIdx.x;
    if (i < TSTEPS + 2) g_cnt[i] = 0;
}

// step 0: v[1], s[1] from initial state; emits tau=0 outputs; seeds states + spike bytes slot 1
__global__ void k_init(const float* __restrict__ v0p, const float* __restrict__ I0p,
                       const int* __restrict__ types, float* __restrict__ out) {
    int n = blockIdx.x * 256 + threadIdx.x;
    bool exc = (types[n] == 1);
    float beta = exc ? BETA_E_F : BETA_I_F;
    float rc   = exc ? RC_E_F   : RC_I_F;
    uint32_t bits = 0;
#pragma unroll
    for (int b = 0; b < 8; ++b) {
        int gi = b * N_NEUR + n;
        float v0 = v0p[gi], I0 = I0p[gi];
        float v = U_REST_F + (v0 - U_REST_F) * beta + I0 * rc;
        bool s = (v >= THETA_F);
        float vr = s ? U_RESET_F : v;
        out[(size_t)(b * TSTEPS + 0) * N_NEUR + n] = s ? 1.0f : 0.0f;
        out[STRIDE_OUT + (size_t)(b * TSTEPS + 0) * N_NEUR + n] = vr;
        g_vr[gi] = vr;
        g_I[gi]  = I0;
        bits |= (s ? 1u : 0u) << b;
    }
    g_sb[1 * N_NEUR + n] = (uint8_t)bits;
}

// Persistent: 256 blocks (1/CU) x 512 threads; all 1000 steps in one dispatch.
__global__ void __launch_bounds__(512, 2)
k_persist(const int* __restrict__ types, float* __restrict__ out) {
    __shared__ __attribute__((aligned(16))) uint32_t swz[1152];
    __shared__ __attribute__((aligned(16))) float red[8][64][4];
    __shared__ unsigned long long wb[2];

    const int tid  = threadIdx.x;
    const int lane = tid & 63;
    const int w    = tid >> 6;
    const int blk  = blockIdx.x;
    const int stripe  = ((blk & 7) << 5) | (blk >> 3);
    const int colbase = stripe << 4;

    // ---- load this wave's B slice into registers (stays resident all 1000 steps)
    short8 Breg[KB_PW];
    {
        const short8* Bp = (const short8*)g_B + ((size_t)stripe * KB_TOT + w * KB_PW) * 64 + lane;
#pragma unroll
        for (int i = 0; i < KB_PW; ++i) Breg[i] = Bp[i * 64];
    }

    // ---- epilogue-thread state in registers
    float Ireg = 0.f, vr = 0.f, beta = 0.f, rc = 0.f;
    int n = 0, b = 0;
    if (tid < 128) {
        b = tid >> 4;
        int nl = tid & 15;
        n = colbase + nl;
        int gi = b * N_NEUR + n;
        Ireg = g_I[gi];
        vr   = g_vr[gi];
        bool exc = (types[n] == 1);
        beta = exc ? BETA_E_F : BETA_I_F;
        rc   = exc ? RC_E_F   : RC_I_F;
    }

    const uint32_t msk = ((lane & 15) < 8) ? 0x00010001u : 0u;
    const int sA = lane & 7, sB = sA + 8;
    const int aoff = (lane >> 4) * 2;
    const int kb0 = w * KB_PW;

    for (int t = 1; t <= TSTEPS; ++t) {
        // ---- wait for all 256 blocks to have published s[t] (t>=2)
        if (t > 1) {
            if (tid == 0) {
                while (__hip_atomic_load(&g_cnt[t], __ATOMIC_RELAXED, __HIP_MEMORY_SCOPE_AGENT) < 256u)
                    __builtin_amdgcn_s_sleep(2);
                __threadfence();
            }
            __syncthreads();
        }
        // ---- stage spike + input mask words (middle-byte-swapped per 4-group)
        {
            const uint32_t* sp = (const uint32_t*)(g_sb + (t & 1) * N_NEUR);
            const uint32_t* ip = (const uint32_t*)(g_inb + (size_t)(t - 1) * N_IN);
            for (int i = tid; i < 1152; i += 512) {
                uint32_t x = (i < 1024)
                    ? __hip_atomic_load(&sp[i], __ATOMIC_RELAXED, __HIP_MEMORY_SCOPE_AGENT)
                    : ip[i - 1024];
                swz[i] = (x & 0xFF0000FFu) | ((x & 0x0000FF00u) << 8) | ((x >> 8) & 0x0000FF00u);
            }
        }
        __syncthreads();

        // ---- MFMA over this wave's 18 k-blocks, B from registers
        f32x4 acc = {0.f, 0.f, 0.f, 0.f};
#pragma unroll
        for (int it = 0; it < KB_PW; ++it) {
            int kb = kb0 + it;
            uint32_t w0 = swz[kb * 8 + aoff];
            uint32_t w1 = swz[kb * 8 + aoff + 1];
            uint32_t a0 = ((w0 >> sA) & msk) * 0x3F80u;
            uint32_t a1 = ((w0 >> sB) & msk) * 0x3F80u;
            uint32_t a2 = ((w1 >> sA) & msk) * 0x3F80u;
            uint32_t a3 = ((w1 >> sB) & msk) * 0x3F80u;
            i32x4 ai = { (int)a0, (int)a1, (int)a2, (int)a3 };
            short8 av = __builtin_bit_cast(short8, ai);
            acc = __builtin_amdgcn_mfma_f32_16x16x32_bf16(av, Breg[it], acc, 0, 0, 0);
        }
        *(f32x4*)&red[w][lane][0] = acc;
        __syncthreads();

        // ---- epilogue: 128 threads own (batch b, local col nl)
        if (tid < 128) {
            int nl = tid & 15;
            int rl = (b >> 2) * 16 + nl, rr = b & 3;
            float S = 0.f;
#pragma unroll
            for (int q = 0; q < 8; ++q) S += red[q][rl][rr];
            float Inew = Ireg * ALPHA_F + S;
            out[2 * STRIDE_OUT + (size_t)(b * TSTEPS + (t - 1)) * N_NEUR + n] = Inew;
            Ireg = Inew;
            if (t < TSTEPS) {
                float v = U_REST_F + (vr - U_REST_F) * beta + Inew * rc;
                bool sbit = (v >= THETA_F);
                float vn = sbit ? U_RESET_F : v;
                out[(size_t)(b * TSTEPS + t) * N_NEUR + n] = sbit ? 1.0f : 0.0f;
                out[STRIDE_OUT + (size_t)(b * TSTEPS + t) * N_NEUR + n] = vn;
                vr = vn;
                unsigned long long bal = __ballot(sbit);  // wave0: b0..3, wave1: b4..7
                if ((tid & 63) == 0) wb[tid >> 6] = bal;
            }
        }
        __syncthreads();

        // ---- publish s[t+1]: 4 u32 words (agent atomics), then arrive on counter
        if (t < TSTEPS) {
            if (tid < 4) {
                unsigned long long b0 = wb[0], b1 = wb[1];
                uint32_t word = 0;
#pragma unroll
                for (int u = 0; u < 4; ++u) {
                    int nn = tid * 4 + u;
                    uint32_t byte = 0;
#pragma unroll
                    for (int q = 0; q < 4; ++q) {
                        byte |= (uint32_t)((b0 >> (nn + 16 * q)) & 1ull) << q;
                        byte |= (uint32_t)((b1 >> (nn + 16 * q)) & 1ull) << (q + 4);
                    }
                    word |= byte << (8 * u);
                }
                uint32_t* dst = (uint32_t*)(g_sb + ((t + 1) & 1) * N_NEUR);
                __hip_atomic_store(&dst[stripe * 4 + tid], word,
                                   __ATOMIC_RELAXED, __HIP_MEMORY_SCOPE_AGENT);
                __threadfence();
            }
            __syncthreads();   // drains vmcnt: all 4 words at coherence point
            if (tid == 0)
                __hip_atomic_fetch_add(&g_cnt[t + 1], 1u,
                                       __ATOMIC_RELEASE, __HIP_MEMORY_SCOPE_AGENT);
        }
    }
}

extern "C" void kernel_launch(void* const* d_in, const int* in_sizes, int n_in,
                              void* d_out, int out_size, void* d_ws, size_t ws_size,
                              hipStream_t stream) {
    const int*   types = (const int*)d_in[0];
    const float* Wrec  = (const float*)d_in[1];
    const float* FF    = (const float*)d_in[2];
    const float* inp   = (const float*)d_in[3];
    const float* v0    = (const float*)d_in[4];
    const float* I0    = (const float*)d_in[5];
    float* out = (float*)d_out;
    (void)in_sizes; (void)n_in; (void)out_size; (void)d_ws; (void)ws_size;

    hipLaunchKernelGGL(prep_w,  dim3(8192), dim3(256), 0, stream, Wrec, types);
    hipLaunchKernelGGL(prep_ff, dim3(1024), dim3(256), 0, stream, FF);
    hipLaunchKernelGGL(prep_in, dim3(512),  dim3(256), 0, stream, inp);
    hipLaunchKernelGGL(k_zero,  dim3(4),    dim3(256), 0, stream);
    hipLaunchKernelGGL(k_init,  dim3(16),   dim3(256), 0, stream, v0, I0, types, out);
    hipLaunchKernelGGL(k_persist, dim3(256), dim3(512), 0, stream, types, out);
}

// Round 4
// 4760.595 us; speedup vs baseline: 3.2954x; 3.2954x over previous
//
#include <hip/hip_runtime.h>
#include <stdint.h>

#define N_NEUR 4096
#define N_IN   512
#define BATCH  8
#define TSTEPS 1000
#define KB_REC 128                 // 128 k-blocks of 32 for recurrent W
#define KB_TOT 144                 // + 16 k-blocks for feedforward (K = 4608)
#define KB_PW  18                  // k-blocks per wave (144 / 8 waves)
#define STRIDE_OUT (BATCH * TSTEPS * N_NEUR)

#define BETA_E_F 0.95122942450071400910f
#define BETA_I_F 0.90483741803595957316f
#define ALPHA_F  0.81873075307798185867f
#define RC_E_F   (100.0f * (1.0f - BETA_E_F))
#define RC_I_F   (100.0f * (1.0f - BETA_I_F))
#define U_REST_F  (-65.0f)
#define THETA_F   (-50.0f)
#define U_RESET_F (-65.0f)

typedef __attribute__((ext_vector_type(8))) short short8;
typedef __attribute__((ext_vector_type(4))) float f32x4;
typedef __attribute__((ext_vector_type(4))) int   i32x4;

// B-fragment-packed weights: [stripe 256][kb 144][lane 64][j 8] bf16
__device__ __attribute__((aligned(16))) uint16_t g_B[256 * KB_TOT * 512];
// tagged spike words, double-buffered by step parity:
//   g_spk[par][i] = (tag<<32) | data32, data32 = spike bytes for neurons 4i..4i+3 (bit b = batch b)
__device__ __attribute__((aligned(16))) unsigned long long g_spk[2][1024];
__device__ __attribute__((aligned(16))) uint8_t g_inb[TSTEPS * N_IN]; // input bitmask bytes
__device__ float g_I[BATCH * N_NEUR];
__device__ float g_vr[BATCH * N_NEUR];

__device__ __forceinline__ uint16_t f2bf(float v) {
    uint32_t x = __float_as_uint(v);
    uint32_t r = x + 0x7FFFu + ((x >> 16) & 1u);
    return (uint16_t)(r >> 16);
}
__device__ __forceinline__ uint32_t bswz(uint32_t x) {  // middle-byte swap per 4-group
    return (x & 0xFF0000FFu) | ((x & 0x0000FF00u) << 8) | ((x >> 8) & 0x0000FF00u);
}

__global__ void prep_w(const float* __restrict__ W, const int* __restrict__ types) {
    int o = blockIdx.x * 256 + threadIdx.x;          // 2,097,152 threads
    int lane = o & 63, kb = (o >> 6) & 127, stripe = o >> 13;
    int col = (stripe << 4) + (lane & 15);
    float scale = (types[col] == 1) ? 0.5f : 2.0f;
    int kbase = kb * 32 + ((lane >> 4) & 3) * 8;
    uint32_t u[4];
#pragma unroll
    for (int p = 0; p < 4; ++p) {
        float v0 = W[(size_t)(kbase + 2 * p) * N_NEUR + col] * scale;
        float v1 = W[(size_t)(kbase + 2 * p + 1) * N_NEUR + col] * scale;
        u[p] = (uint32_t)f2bf(v0) | ((uint32_t)f2bf(v1) << 16);
    }
    i32x4 iv = { (int)u[0], (int)u[1], (int)u[2], (int)u[3] };
    ((short8*)g_B)[(stripe * KB_TOT + kb) * 64 + lane] = __builtin_bit_cast(short8, iv);
}

__global__ void prep_ff(const float* __restrict__ FF) {
    int o = blockIdx.x * 256 + threadIdx.x;          // 262,144 threads
    int lane = o & 63, kbl = (o >> 6) & 15, stripe = o >> 10;
    int col = (stripe << 4) + (lane & 15);
    int kbase = kbl * 32 + ((lane >> 4) & 3) * 8;
    uint32_t u[4];
#pragma unroll
    for (int p = 0; p < 4; ++p) {
        float v0 = FF[(size_t)(kbase + 2 * p) * N_NEUR + col];
        float v1 = FF[(size_t)(kbase + 2 * p + 1) * N_NEUR + col];
        u[p] = (uint32_t)f2bf(v0) | ((uint32_t)f2bf(v1) << 16);
    }
    i32x4 iv = { (int)u[0], (int)u[1], (int)u[2], (int)u[3] };
    ((short8*)g_B)[(stripe * KB_TOT + 128 + kbl) * 64 + lane] = __builtin_bit_cast(short8, iv);
}

__global__ void prep_in(const float* __restrict__ inp) {
    const int total = TSTEPS * N_IN;
    for (int o = blockIdx.x * 256 + threadIdx.x; o < total; o += gridDim.x * 256) {
        int t = o >> 9, i = o & 511;
        uint32_t m = 0;
#pragma unroll
        for (int b = 0; b < 8; ++b) {
            float v = inp[(size_t)(b * TSTEPS + t) * N_IN + i];
            m |= (v != 0.0f ? 1u : 0u) << b;
        }
        g_inb[o] = (uint8_t)m;
    }
}

__global__ void k_zero() {   // clear both spike-word buffers (replay safety)
    int i = blockIdx.x * 256 + threadIdx.x;
    if (i < 2048) ((unsigned long long*)g_spk)[i] = 0ull;
}

// step 0: v[1], s[1] from initial state; emits tau=0 outputs; seeds states + tagged words (tag=1)
__global__ void k_init(const float* __restrict__ v0p, const float* __restrict__ I0p,
                       const int* __restrict__ types, float* __restrict__ out) {
    __shared__ uint8_t sb[256];
    int n = blockIdx.x * 256 + threadIdx.x;
    bool exc = (types[n] == 1);
    float beta = exc ? BETA_E_F : BETA_I_F;
    float rc   = exc ? RC_E_F   : RC_I_F;
    uint32_t bits = 0;
#pragma unroll
    for (int b = 0; b < 8; ++b) {
        int gi = b * N_NEUR + n;
        float v0 = v0p[gi], I0 = I0p[gi];
        float v = U_REST_F + (v0 - U_REST_F) * beta + I0 * rc;
        bool s = (v >= THETA_F);
        float vr = s ? U_RESET_F : v;
        out[(size_t)(b * TSTEPS + 0) * N_NEUR + n] = s ? 1.0f : 0.0f;
        out[STRIDE_OUT + (size_t)(b * TSTEPS + 0) * N_NEUR + n] = vr;
        g_vr[gi] = vr;
        g_I[gi]  = I0;
        bits |= (s ? 1u : 0u) << b;
    }
    sb[threadIdx.x] = (uint8_t)bits;
    __syncthreads();
    if (threadIdx.x < 64) {
        int l = threadIdx.x * 4;
        uint32_t w = (uint32_t)sb[l] | ((uint32_t)sb[l + 1] << 8)
                   | ((uint32_t)sb[l + 2] << 16) | ((uint32_t)sb[l + 3] << 24);
        g_spk[1][blockIdx.x * 64 + threadIdx.x] = (1ull << 32) | (unsigned long long)w;
    }
}

// Persistent: 256 blocks (1/CU) x 512 threads; all 1000 steps in one dispatch.
// Sync = tagged u64 dataflow words, relaxed agent atomics, no fences, no RMW.
__global__ void __launch_bounds__(512, 2)
k_persist(const int* __restrict__ types, float* __restrict__ out) {
    __shared__ __attribute__((aligned(16))) uint32_t swz[1152];
    __shared__ __attribute__((aligned(16))) float red[8][64][4];
    __shared__ unsigned long long wb[2];

    const int tid  = threadIdx.x;
    const int lane = tid & 63;
    const int w    = tid >> 6;
    const int blk  = blockIdx.x;
    const int stripe  = ((blk & 7) << 5) | (blk >> 3);
    const int colbase = stripe << 4;

    // ---- this wave's B slice into registers (resident all 1000 steps)
    short8 Breg[KB_PW];
    {
        const short8* Bp = (const short8*)g_B + ((size_t)stripe * KB_TOT + w * KB_PW) * 64 + lane;
#pragma unroll
        for (int i = 0; i < KB_PW; ++i) Breg[i] = Bp[i * 64];
    }

    // ---- epilogue-thread state in registers
    float Ireg = 0.f, vr = 0.f, beta = 0.f, rc = 0.f;
    int n = 0, b = 0;
    if (tid < 128) {
        b = tid >> 4;
        int nl = tid & 15;
        n = colbase + nl;
        int gi = b * N_NEUR + n;
        Ireg = g_I[gi];
        vr   = g_vr[gi];
        bool exc = (types[n] == 1);
        beta = exc ? BETA_E_F : BETA_I_F;
        rc   = exc ? RC_E_F   : RC_I_F;
    }

    const uint32_t msk = ((lane & 15) < 8) ? 0x00010001u : 0u;
    const int sA = lane & 7, sB = sA + 8;
    const int aoff = (lane >> 4) * 2;
    const int kb0 = w * KB_PW;

    for (int t = 1; t <= TSTEPS; ++t) {
        // ---- stage: distributed poll on tagged words (2 per thread), then swizzle into LDS
        {
            const unsigned long long* sp = g_spk[t & 1];
            const int i0 = tid, i1 = tid + 512;
            unsigned long long v0 = 0, v1 = 0;
            bool d0 = false, d1 = false;
            while (true) {
                if (!d0) { v0 = __hip_atomic_load(&sp[i0], __ATOMIC_RELAXED, __HIP_MEMORY_SCOPE_AGENT);
                           d0 = ((uint32_t)(v0 >> 32) == (uint32_t)t); }
                if (!d1) { v1 = __hip_atomic_load(&sp[i1], __ATOMIC_RELAXED, __HIP_MEMORY_SCOPE_AGENT);
                           d1 = ((uint32_t)(v1 >> 32) == (uint32_t)t); }
                if (d0 && d1) break;
                __builtin_amdgcn_s_sleep(1);
            }
            swz[i0] = bswz((uint32_t)v0);
            swz[i1] = bswz((uint32_t)v1);
            if (tid < 128) {
                uint32_t x = ((const uint32_t*)(g_inb + (size_t)(t - 1) * N_IN))[tid];
                swz[1024 + tid] = bswz(x);
            }
        }
        __syncthreads();   // also drains prev-iter output stores (overlapped with poll)

        // ---- MFMA over this wave's 18 k-blocks, B from registers
        f32x4 acc = {0.f, 0.f, 0.f, 0.f};
#pragma unroll
        for (int it = 0; it < KB_PW; ++it) {
            int kb = kb0 + it;
            uint32_t w0 = swz[kb * 8 + aoff];
            uint32_t w1 = swz[kb * 8 + aoff + 1];
            uint32_t a0 = ((w0 >> sA) & msk) * 0x3F80u;
            uint32_t a1 = ((w0 >> sB) & msk) * 0x3F80u;
            uint32_t a2 = ((w1 >> sA) & msk) * 0x3F80u;
            uint32_t a3 = ((w1 >> sB) & msk) * 0x3F80u;
            i32x4 ai = { (int)a0, (int)a1, (int)a2, (int)a3 };
            short8 av = __builtin_bit_cast(short8, ai);
            acc = __builtin_amdgcn_mfma_f32_16x16x32_bf16(av, Breg[it], acc, 0, 0, 0);
        }
        *(f32x4*)&red[w][lane][0] = acc;
        __syncthreads();

        // ---- epilogue: compute spikes FIRST (publish before output stores)
        float Inew = 0.f, vn = 0.f;
        bool sbit = false;
        if (tid < 128) {
            int nl = tid & 15;
            int rl = (b >> 2) * 16 + nl, rr = b & 3;
            float S = 0.f;
#pragma unroll
            for (int q = 0; q < 8; ++q) S += red[q][rl][rr];
            Inew = Ireg * ALPHA_F + S;
            Ireg = Inew;
            if (t < TSTEPS) {
                float v = U_REST_F + (vr - U_REST_F) * beta + Inew * rc;
                sbit = (v >= THETA_F);
                vn = sbit ? U_RESET_F : v;
                vr = vn;
            }
            unsigned long long bal = __ballot(sbit);  // wave0: b0..3, wave1: b4..7
            if ((tid & 63) == 0) wb[tid >> 6] = bal;
        }
        __syncthreads();   // cheap: no global ops pending since last barrier

        // ---- publish s[t+1] as tagged words, THEN issue output stores
        if (t < TSTEPS && tid < 4) {
            unsigned long long b0 = wb[0], b1 = wb[1];
            uint32_t word = 0;
#pragma unroll
            for (int u = 0; u < 4; ++u) {
                int nn = tid * 4 + u;
                uint32_t byte = 0;
#pragma unroll
                for (int q = 0; q < 4; ++q) {
                    byte |= (uint32_t)((b0 >> (nn + 16 * q)) & 1ull) << q;
                    byte |= (uint32_t)((b1 >> (nn + 16 * q)) & 1ull) << (q + 4);
                }
                word |= byte << (8 * u);
            }
            unsigned long long tg = ((unsigned long long)(t + 1) << 32) | (unsigned long long)word;
            __hip_atomic_store(&g_spk[(t + 1) & 1][stripe * 4 + tid], tg,
                               __ATOMIC_RELAXED, __HIP_MEMORY_SCOPE_AGENT);
        }
        if (tid < 128) {
            out[2 * STRIDE_OUT + (size_t)(b * TSTEPS + (t - 1)) * N_NEUR + n] = Inew;
            if (t < TSTEPS) {
                out[(size_t)(b * TSTEPS + t) * N_NEUR + n] = sbit ? 1.0f : 0.0f;
                out[STRIDE_OUT + (size_t)(b * TSTEPS + t) * N_NEUR + n] = vn;
            }
        }
    }
}

extern "C" void kernel_launch(void* const* d_in, const int* in_sizes, int n_in,
                              void* d_out, int out_size, void* d_ws, size_t ws_size,
                              hipStream_t stream) {
    const int*   types = (const int*)d_in[0];
    const float* Wrec  = (const float*)d_in[1];
    const float* FF    = (const float*)d_in[2];
    const float* inp   = (const float*)d_in[3];
    const float* v0    = (const float*)d_in[4];
    const float* I0    = (const float*)d_in[5];
    float* out = (float*)d_out;
    (void)in_sizes; (void)n_in; (void)out_size; (void)d_ws; (void)ws_size;

    hipLaunchKernelGGL(prep_w,  dim3(8192), dim3(256), 0, stream, Wrec, types);
    hipLaunchKernelGGL(prep_ff, dim3(1024), dim3(256), 0, stream, FF);
    hipLaunchKernelGGL(prep_in, dim3(512),  dim3(256), 0, stream, inp);
    hipLaunchKernelGGL(k_zero,  dim3(8),    dim3(256), 0, stream);
    hipLaunchKernelGGL(k_init,  dim3(16),   dim3(256), 0, stream, v0, I0, types, out);
    hipLaunchKernelGGL(k_persist, dim3(256), dim3(512), 0, stream, types, out);
}